// Round 3
// baseline (800.906 us; speedup 1.0000x reference)
//
#include <hip/hip_runtime.h>

typedef _Float16 h16;
typedef _Float16 h16x8 __attribute__((ext_vector_type(8)));
typedef float    f32x4 __attribute__((ext_vector_type(4)));

static constexpr int NN  = 32768;
static constexpr int EE  = 262144;
static constexpr int TT  = 262144;
static constexpr int D   = 128;   // DN = DE
static constexpr int K3  = 640;   // 3*DN + 2*DE
static constexpr int LDA = 72;    // padded LDS row stride (64 + 8) in h16
#define EPS 1e-5f

// ---------------------------------------------------------------------------
// fp32 -> fp16 converter, 8 elems/thread
// ---------------------------------------------------------------------------
__global__ __launch_bounds__(256) void cvt_f32_f16(
    const float* __restrict__ src, h16* __restrict__ dst, int n8)
{
    const int i = blockIdx.x * 256 + threadIdx.x;
    if (i >= n8) return;
    const float4* s = reinterpret_cast<const float4*>(src);
    const float4 a = s[2 * i], b = s[2 * i + 1];
    h16x8 o;
    o[0] = (h16)a.x; o[1] = (h16)a.y; o[2] = (h16)a.z; o[3] = (h16)a.w;
    o[4] = (h16)b.x; o[5] = (h16)b.y; o[6] = (h16)b.z; o[7] = (h16)b.w;
    *reinterpret_cast<h16x8*>(dst + 8 * i) = o;
}

// ---------------------------------------------------------------------------
// c3: gathered A [T,640](fp16) @ W3^T [640,256](fp16) + b3 -> LN(256) ->
// sigmoid*tanh -> atomicAdd scatter into acc3[E,128] (fp32, = d_out)
// Block 256 thr = 4 waves in a 2x2 grid; each wave owns a 64-row x 128-col
// output tile (LDS reads per chunk: 24/wave vs 36 for the 32x256 split).
// Column tiles are interleaved so the sigmoid/tanh gate pairs stay in-wave;
// LN(256) row sums use one LDS partial exchange.
// One-deep software pipeline: chunk c+1's gathers issue before MFMA(c).
// ---------------------------------------------------------------------------
__global__ __launch_bounds__(256, 2) void c3_kernel(
    const h16*  __restrict__ nodeh, const float* __restrict__ edge,
    const h16*  __restrict__ edgeh,
    const int* __restrict__ idx_i, const int* __restrict__ idx_j,
    const int* __restrict__ idx_k, const int* __restrict__ idx_ji,
    const int* __restrict__ idx_kj,
    const h16* __restrict__ W3h, const float* __restrict__ b3,
    const float* __restrict__ g3, const float* __restrict__ be3,
    float* __restrict__ acc3)
{
    __shared__ h16 As[128 * LDA];       // 18 KB
    __shared__ h16 Bs[256 * LDA];       // 36 KB
    __shared__ float2 Ps[128][2];       // 2 KB: LN(256) partials [row][wn]

    const int tid  = threadIdx.x;
    const int lane = tid & 63;
    const int wave = tid >> 6;
    const int wm   = wave >> 1;         // 0..1: row half
    const int wn   = wave & 1;          // 0..1: col interleave group
    const int l15  = lane & 15;
    const int quad = lane >> 4;
    const int m0   = blockIdx.x * 128;

    f32x4 acc[4][8];                    // [mt][nt]; nt<4 = filter tiles, nt>=4 = core tiles
    #pragma unroll
    for (int mt = 0; mt < 4; ++mt)
        #pragma unroll
        for (int nt = 0; nt < 8; ++nt)
            acc[mt][nt] = (f32x4){0.f, 0.f, 0.f, 0.f};

    const int r = tid >> 1;   // A staging: 2 threads per row
    const int h = tid & 1;    // which 32-elem half of the 64-col chunk

    const size_t rI  = (size_t)idx_i [m0 + r];
    const size_t rJ  = (size_t)idx_j [m0 + r];
    const size_t rK  = (size_t)idx_k [m0 + r];
    const size_t rJI = (size_t)idx_ji[m0 + r];
    const size_t rKJ = (size_t)idx_kj[m0 + r];

    h16x8 av[4], bv[8];

#define LDC3(c)                                                                          \
    {                                                                                    \
        const int seg  = (c) >> 1;                                                       \
        const int half = (c) & 1;                                                        \
        const size_t row = (seg == 0) ? rI : (seg == 1) ? rJ                             \
                         : (seg == 2) ? rK : (seg == 3) ? rJI : rKJ;                     \
        if (seg < 3) {                                                                   \
            const h16x8* sp = reinterpret_cast<const h16x8*>(                            \
                nodeh + row * D + half * 64 + h * 32);                                   \
            _Pragma("unroll")                                                            \
            for (int q = 0; q < 4; ++q) av[q] = sp[q];                                   \
        } else if (edgeh) {                                                              \
            const h16x8* sp = reinterpret_cast<const h16x8*>(                            \
                edgeh + row * D + half * 64 + h * 32);                                   \
            _Pragma("unroll")                                                            \
            for (int q = 0; q < 4; ++q) av[q] = sp[q];                                   \
        } else {                                                                         \
            const float4* fp = reinterpret_cast<const float4*>(                          \
                edge + row * D + half * 64 + h * 32);                                    \
            _Pragma("unroll")                                                            \
            for (int q = 0; q < 4; ++q) {                                                \
                const float4 u = fp[2 * q], vv = fp[2 * q + 1];                          \
                h16x8 t;                                                                 \
                t[0] = (h16)u.x;  t[1] = (h16)u.y;  t[2] = (h16)u.z;  t[3] = (h16)u.w;   \
                t[4] = (h16)vv.x; t[5] = (h16)vv.y; t[6] = (h16)vv.z; t[7] = (h16)vv.w;  \
                av[q] = t;                                                               \
            }                                                                            \
        }                                                                                \
        const h16x8* wp = reinterpret_cast<const h16x8*>(                                \
            W3h + (size_t)tid * K3 + (c) * 64);                                          \
        _Pragma("unroll")                                                                \
        for (int q = 0; q < 8; ++q) bv[q] = wp[q];                                       \
    }

    LDC3(0);   // prologue prefetch

    #pragma unroll 1
    for (int c = 0; c < 10; ++c) {
        __syncthreads();
        h16x8* ad = reinterpret_cast<h16x8*>(&As[r * LDA + h * 32]);
        #pragma unroll
        for (int q = 0; q < 4; ++q) ad[q] = av[q];
        h16x8* bd = reinterpret_cast<h16x8*>(&Bs[tid * LDA]);
        #pragma unroll
        for (int q = 0; q < 8; ++q) bd[q] = bv[q];
        __syncthreads();

        if (c < 9) LDC3(c + 1);   // issue next chunk's gathers under MFMA

        #pragma unroll
        for (int kk = 0; kk < 64; kk += 32) {
            h16x8 a[4];
            #pragma unroll
            for (int mt = 0; mt < 4; ++mt)
                a[mt] = *reinterpret_cast<const h16x8*>(
                    &As[(wm*64 + mt*16 + l15) * LDA + kk + quad*8]);
            #pragma unroll
            for (int nt = 0; nt < 8; ++nt) {
                const int p = (nt < 4) ? (wn*4 + nt) : (8 + wn*4 + nt - 4);
                h16x8 b = *reinterpret_cast<const h16x8*>(
                    &Bs[(p*16 + l15) * LDA + kk + quad*8]);
                #pragma unroll
                for (int mt = 0; mt < 4; ++mt)
                    acc[mt][nt] = __builtin_amdgcn_mfma_f32_16x16x32_f16(a[mt], b, acc[mt][nt], 0, 0, 0);
            }
        }
    }
#undef LDC3

    // ---- epilogue: +b3, LN(256) with cross-wave partial exchange, gate,
    //      atomic scatter ----
    float bias[2][4], gg[2][4], bb[2][4];
    #pragma unroll
    for (int hf = 0; hf < 2; ++hf)
        #pragma unroll
        for (int q = 0; q < 4; ++q) {
            const int cc = hf*128 + (wn*4 + q)*16 + l15;
            bias[hf][q] = b3[cc]; gg[hf][q] = g3[cc]; bb[hf][q] = be3[cc];
        }

    float sA[4][4], s2A[4][4];
    #pragma unroll
    for (int mt = 0; mt < 4; ++mt) {
        #pragma unroll
        for (int rg = 0; rg < 4; ++rg) {
            float s = 0.f, s2 = 0.f;
            #pragma unroll
            for (int nt = 0; nt < 8; ++nt) {
                const float x = acc[mt][nt][rg] + bias[nt >> 2][nt & 3];
                s += x; s2 += x * x;
            }
            #pragma unroll
            for (int m = 1; m < 16; m <<= 1) {
                s  += __shfl_xor(s,  m, 64);
                s2 += __shfl_xor(s2, m, 64);
            }
            sA[mt][rg] = s; s2A[mt][rg] = s2;
            if (l15 == 0)
                Ps[wm*64 + mt*16 + quad*4 + rg][wn] = make_float2(s, s2);
        }
    }
    __syncthreads();
    #pragma unroll
    for (int mt = 0; mt < 4; ++mt) {
        #pragma unroll
        for (int rg = 0; rg < 4; ++rg) {
            const int rl = wm*64 + mt*16 + quad*4 + rg;
            const float2 po = Ps[rl][wn ^ 1];
            const float S  = sA[mt][rg]  + po.x;
            const float S2 = s2A[mt][rg] + po.y;
            const float mean = S * (1.f / 256.f);
            const float var  = S2 * (1.f / 256.f) - mean * mean;
            const float inv  = rsqrtf(var + EPS);
            const size_t e   = (size_t)idx_ji[m0 + rl];
            #pragma unroll
            for (int q = 0; q < 4; ++q) {
                const float f   = (acc[mt][q][rg]     + bias[0][q] - mean) * inv * gg[0][q] + bb[0][q];
                const float co  = (acc[mt][4 + q][rg] + bias[1][q] - mean) * inv * gg[1][q] + bb[1][q];
                const float msg = (1.f / (1.f + __expf(-f))) * tanhf(co);
                atomicAdd(&acc3[e * D + (wn*4 + q)*16 + l15], msg);
            }
        }
    }
}

// ---------------------------------------------------------------------------
// c2 (fused with final): (node[i]*node[j]) [E,128] @ W2^T + b2 -> LN(256) ->
// gate -> LN(128) = c2_emb; then read acc3 row, LN(128) = c3_emb; write
// out = tanh(edge + c2_emb + c3_emb) in place over acc3 (= d_out).
// Old 32x256-per-wave decomposition: each wave holds full 128-col rows, so
// both LNs and the fusion stay in-wave.
// ---------------------------------------------------------------------------
__global__ __launch_bounds__(256, 2) void c2_kernel(
    const h16* __restrict__ nodeh,
    const int* __restrict__ ei, const int* __restrict__ ej,
    const h16* __restrict__ W2h, const float* __restrict__ b2,
    const float* __restrict__ g2, const float* __restrict__ be2,
    const float* __restrict__ g22, const float* __restrict__ be22,
    const float* __restrict__ g32, const float* __restrict__ be32,
    const float* __restrict__ edge,
    float* __restrict__ out)
{
    __shared__ h16 As[128 * LDA];
    __shared__ h16 Bs[256 * LDA];

    const int tid  = threadIdx.x;
    const int lane = tid & 63;
    const int wave = tid >> 6;
    const int l15  = lane & 15;
    const int quad = lane >> 4;
    const int m0   = blockIdx.x * 128;

    f32x4 acc[2][16];
    #pragma unroll
    for (int mt = 0; mt < 2; ++mt)
        #pragma unroll
        for (int nt = 0; nt < 16; ++nt)
            acc[mt][nt] = (f32x4){0.f, 0.f, 0.f, 0.f};

    const int r = tid >> 1;
    const int h = tid & 1;
    const size_t ri = (size_t)ei[m0 + r];
    const size_t rj = (size_t)ej[m0 + r];

    h16x8 av[4], bv[8];

#define LDC2(c)                                                                          \
    {                                                                                    \
        const h16x8* si = reinterpret_cast<const h16x8*>(                                \
            nodeh + ri * D + (c) * 64 + h * 32);                                         \
        const h16x8* sj = reinterpret_cast<const h16x8*>(                                \
            nodeh + rj * D + (c) * 64 + h * 32);                                         \
        _Pragma("unroll")                                                                \
        for (int q = 0; q < 4; ++q) av[q] = si[q] * sj[q];                               \
        const h16x8* wp = reinterpret_cast<const h16x8*>(                                \
            W2h + (size_t)tid * D + (c) * 64);                                           \
        _Pragma("unroll")                                                                \
        for (int q = 0; q < 8; ++q) bv[q] = wp[q];                                       \
    }

    LDC2(0);

    #pragma unroll 1
    for (int c = 0; c < 2; ++c) {
        __syncthreads();
        h16x8* ad = reinterpret_cast<h16x8*>(&As[r * LDA + h * 32]);
        #pragma unroll
        for (int q = 0; q < 4; ++q) ad[q] = av[q];
        h16x8* bd = reinterpret_cast<h16x8*>(&Bs[tid * LDA]);
        #pragma unroll
        for (int q = 0; q < 8; ++q) bd[q] = bv[q];
        __syncthreads();

        if (c < 1) LDC2(c + 1);

        #pragma unroll
        for (int kk = 0; kk < 64; kk += 32) {
            h16x8 a0 = *reinterpret_cast<const h16x8*>(&As[(wave*32      + l15) * LDA + kk + quad*8]);
            h16x8 a1 = *reinterpret_cast<const h16x8*>(&As[(wave*32 + 16 + l15) * LDA + kk + quad*8]);
            #pragma unroll
            for (int nt = 0; nt < 16; ++nt) {
                h16x8 b = *reinterpret_cast<const h16x8*>(&Bs[(nt*16 + l15) * LDA + kk + quad*8]);
                acc[0][nt] = __builtin_amdgcn_mfma_f32_16x16x32_f16(a0, b, acc[0][nt], 0, 0, 0);
                acc[1][nt] = __builtin_amdgcn_mfma_f32_16x16x32_f16(a1, b, acc[1][nt], 0, 0, 0);
            }
        }
    }
#undef LDC2

    // ---- epilogue: +b2, LN(256), gate, LN(128), then fused final ----
    float bias[16], gg[16], bb[16];
    #pragma unroll
    for (int nt = 0; nt < 16; ++nt) {
        const int cc = nt * 16 + l15;
        bias[nt] = b2[cc]; gg[nt] = g2[cc]; bb[nt] = be2[cc];
    }
    float g2c[8], b2c[8], g3c[8], b3c[8];
    #pragma unroll
    for (int nt = 0; nt < 8; ++nt) {
        const int cc = nt * 16 + l15;
        g2c[nt] = g22[cc]; b2c[nt] = be22[cc];
        g3c[nt] = g32[cc]; b3c[nt] = be32[cc];
    }
    #pragma unroll
    for (int mt = 0; mt < 2; ++mt) {
        #pragma unroll
        for (int rg = 0; rg < 4; ++rg) {
            float v[16];
            float s = 0.f, s2 = 0.f;
            #pragma unroll
            for (int nt = 0; nt < 16; ++nt) {
                v[nt] = acc[mt][nt][rg] + bias[nt];
                s += v[nt]; s2 += v[nt] * v[nt];
            }
            #pragma unroll
            for (int m = 1; m < 16; m <<= 1) {
                s  += __shfl_xor(s,  m, 64);
                s2 += __shfl_xor(s2, m, 64);
            }
            const float mean = s * (1.f / 256.f);
            const float var  = s2 * (1.f / 256.f) - mean * mean;
            const float inv  = rsqrtf(var + EPS);
            const size_t rowg = (size_t)(m0 + wave * 32 + mt * 16 + quad * 4 + rg);

            // gate -> msg, and read this row's acc3 (c3 accumulator)
            float msg[8], a3[8];
            float t = 0.f, t2 = 0.f, u = 0.f, u2 = 0.f;
            #pragma unroll
            for (int nt = 0; nt < 8; ++nt) {
                const float f  = (v[nt]     - mean) * inv * gg[nt]     + bb[nt];
                const float co = (v[nt + 8] - mean) * inv * gg[nt + 8] + bb[nt + 8];
                const float m_ = (1.f / (1.f + __expf(-f))) * tanhf(co);
                msg[nt] = m_; t += m_; t2 += m_ * m_;
                const float a_ = out[rowg * D + nt * 16 + l15];
                a3[nt] = a_; u += a_; u2 += a_ * a_;
            }
            #pragma unroll
            for (int m = 1; m < 16; m <<= 1) {
                t  += __shfl_xor(t,  m, 64);
                t2 += __shfl_xor(t2, m, 64);
                u  += __shfl_xor(u,  m, 64);
                u2 += __shfl_xor(u2, m, 64);
            }
            const float mean2 = t * (1.f / 128.f);
            const float var2  = t2 * (1.f / 128.f) - mean2 * mean2;
            const float inv2  = rsqrtf(var2 + EPS);
            const float mean3 = u * (1.f / 128.f);
            const float var3  = u2 * (1.f / 128.f) - mean3 * mean3;
            const float inv3  = rsqrtf(var3 + EPS);
            #pragma unroll
            for (int nt = 0; nt < 8; ++nt) {
                const int cc = nt * 16 + l15;
                const float c2v = (msg[nt] - mean2) * inv2 * g2c[nt] + b2c[nt];
                const float c3v = (a3[nt]  - mean3) * inv3 * g3c[nt] + b3c[nt];
                const float ev  = edge[rowg * D + cc];
                out[rowg * D + cc] = tanhf(ev + c2v + c3v);
            }
        }
    }
}

// ---------------------------------------------------------------------------
extern "C" void kernel_launch(void* const* d_in, const int* in_sizes, int n_in,
                              void* d_out, int out_size, void* d_ws, size_t ws_size,
                              hipStream_t stream)
{
    const float* node   = (const float*)d_in[0];
    const float* edge   = (const float*)d_in[1];
    const int*   e_i    = (const int*)d_in[2];
    const int*   e_j    = (const int*)d_in[3];
    const int*   idx_i  = (const int*)d_in[4];
    const int*   idx_j  = (const int*)d_in[5];
    const int*   idx_k  = (const int*)d_in[6];
    const int*   idx_ji = (const int*)d_in[7];
    const int*   idx_kj = (const int*)d_in[8];
    const float* W2     = (const float*)d_in[9];
    const float* b2     = (const float*)d_in[10];
    const float* W3     = (const float*)d_in[11];
    const float* b3     = (const float*)d_in[12];
    const float* g_c2   = (const float*)d_in[13];
    const float* be_c2  = (const float*)d_in[14];
    const float* g_c3   = (const float*)d_in[15];
    const float* be_c3  = (const float*)d_in[16];
    const float* g_c22  = (const float*)d_in[17];
    const float* be_c22 = (const float*)d_in[18];
    const float* g_c32  = (const float*)d_in[19];
    const float* be_c32 = (const float*)d_in[20];

    // ws layout (fp16): W3h [256*640] | W2h [256*128] | nodeh [N*128] |
    //                   edgeh [E*128] (optional)
    h16* W3h   = (h16*)d_ws;
    h16* W2h   = W3h + 256 * K3;
    h16* nodeh = W2h + 256 * D;
    h16* edgeh = nodeh + (size_t)NN * D;
    const size_t need = ((size_t)256 * K3 + 256 * D + (size_t)NN * D
                         + (size_t)EE * D) * sizeof(h16);
    const bool use_edgeh = ws_size >= need;

    float* acc3 = (float*)d_out;   // fp32 scatter accumulator, finalized in place
    float* out  = (float*)d_out;

    hipMemsetAsync(d_out, 0, (size_t)EE * D * sizeof(float), stream);
    cvt_f32_f16<<<dim3((256 * K3 / 8 + 255) / 256), dim3(256), 0, stream>>>(W3, W3h, 256 * K3 / 8);
    cvt_f32_f16<<<dim3((256 * D  / 8 + 255) / 256), dim3(256), 0, stream>>>(W2, W2h, 256 * D / 8);
    cvt_f32_f16<<<dim3((NN * D   / 8 + 255) / 256), dim3(256), 0, stream>>>(node, nodeh, NN * D / 8);
    if (use_edgeh)
        cvt_f32_f16<<<dim3((EE * D / 8 + 255) / 256), dim3(256), 0, stream>>>(edge, edgeh, EE * D / 8);

    c3_kernel<<<dim3(TT / 128), dim3(256), 0, stream>>>(
        nodeh, edge, use_edgeh ? edgeh : (const h16*)nullptr,
        idx_i, idx_j, idx_k, idx_ji, idx_kj, W3h, b3, g_c3, be_c3, acc3);
    c2_kernel<<<dim3(EE / 128), dim3(256), 0, stream>>>(
        nodeh, e_i, e_j, W2h, b2, g_c2, be_c2, g_c22, be_c22,
        g_c32, be_c32, edge, out);
}

// Round 4
// 715.090 us; speedup vs baseline: 1.1200x; 1.1200x over previous
//
#include <hip/hip_runtime.h>

typedef _Float16 h16;
typedef _Float16 h16x8 __attribute__((ext_vector_type(8)));
typedef float    f32x4 __attribute__((ext_vector_type(4)));

static constexpr int NN  = 32768;
static constexpr int EE  = 262144;
static constexpr int TT  = 262144;
static constexpr int D   = 128;   // DN = DE
static constexpr int K3  = 640;   // 3*DN + 2*DE
static constexpr int LDA = 72;    // padded LDS row stride (64 + 8) in h16
#define EPS 1e-5f

// ---------------------------------------------------------------------------
// fp32 -> fp16 converter, 8 elems/thread (row-major, layout-preserving)
// ---------------------------------------------------------------------------
__global__ __launch_bounds__(256) void cvt_f32_f16(
    const float* __restrict__ src, h16* __restrict__ dst, int n8)
{
    const int i = blockIdx.x * 256 + threadIdx.x;
    if (i >= n8) return;
    const float4* s = reinterpret_cast<const float4*>(src);
    const float4 a = s[2 * i], b = s[2 * i + 1];
    h16x8 o;
    o[0] = (h16)a.x; o[1] = (h16)a.y; o[2] = (h16)a.z; o[3] = (h16)a.w;
    o[4] = (h16)b.x; o[5] = (h16)b.y; o[6] = (h16)b.z; o[7] = (h16)b.w;
    *reinterpret_cast<h16x8*>(dst + 8 * i) = o;
}

// ---------------------------------------------------------------------------
// Weight converter with chunk-major re-layout for coalesced staging loads:
// dst[c][q][n][e]  (c = K-chunk of 64, q = 8-col group, n = 0..255, e = 0..7)
// holds W[n][c*64 + q*8 + e].  A staging load instruction then reads
// 64 lanes x 16 B CONTIGUOUS (16 lines) instead of 64 scattered lines.
// ---------------------------------------------------------------------------
__global__ __launch_bounds__(256) void cvt_w_t(
    const float* __restrict__ src, h16* __restrict__ dst, int K, int n8)
{
    const int t = blockIdx.x * 256 + threadIdx.x;
    if (t >= n8) return;
    const int d   = t * 8;
    const int c   = d >> 14;           // 16384 h16 per chunk
    const int rem = d & 16383;
    const int q   = rem >> 11;         // 2048 h16 per q-group
    const int n   = (rem >> 3) & 255;
    const int k   = c * 64 + q * 8;
    const float4* s = reinterpret_cast<const float4*>(src + (size_t)n * K + k);
    const float4 a = s[0], b = s[1];
    h16x8 o;
    o[0] = (h16)a.x; o[1] = (h16)a.y; o[2] = (h16)a.z; o[3] = (h16)a.w;
    o[4] = (h16)b.x; o[5] = (h16)b.y; o[6] = (h16)b.z; o[7] = (h16)b.w;
    *reinterpret_cast<h16x8*>(dst + d) = o;
}

// ---------------------------------------------------------------------------
// c3: gathered A [T,640](fp16) @ W3^T [640,256](fp16) + b3 -> LN(256) ->
// sigmoid*tanh -> atomicAdd scatter into acc3[E,128] (fp32, = d_out)
// R2-proven 32x256-per-wave MFMA structure; staging restructured for line
// coalescing: A uses 8 threads/row (4 passes of 32 rows), B reads the
// chunk-major W3t layout. One-deep software pipeline.
// ---------------------------------------------------------------------------
__global__ __launch_bounds__(256, 2) void c3_kernel(
    const h16*  __restrict__ nodeh, const float* __restrict__ edge,
    const h16*  __restrict__ edgeh,
    const int* __restrict__ idx_i, const int* __restrict__ idx_j,
    const int* __restrict__ idx_k, const int* __restrict__ idx_ji,
    const int* __restrict__ idx_kj,
    const h16* __restrict__ W3t, const float* __restrict__ b3,
    const float* __restrict__ g3, const float* __restrict__ be3,
    float* __restrict__ acc3)
{
    __shared__ h16 As[128 * LDA];   // 18 KB
    __shared__ h16 Bs[256 * LDA];   // 36 KB

    const int tid  = threadIdx.x;
    const int lane = tid & 63;
    const int wave = tid >> 6;
    const int l15  = lane & 15;
    const int quad = lane >> 4;
    const int m0   = blockIdx.x * 128;

    f32x4 acc[2][16];
    #pragma unroll
    for (int mt = 0; mt < 2; ++mt)
        #pragma unroll
        for (int nt = 0; nt < 16; ++nt)
            acc[mt][nt] = (f32x4){0.f, 0.f, 0.f, 0.f};

    const int r8  = tid >> 3;   // 0..31: row within the 32-row pass group
    const int sub = tid & 7;    // 16-B segment within the row's 128-B chunk

    // hoisted gather rows: rIdx[seg][pass] (rows pass*32 + r8)
    int rIdx[5][4];
    {
        const int* arrs[5] = {idx_i, idx_j, idx_k, idx_ji, idx_kj};
        #pragma unroll
        for (int sg = 0; sg < 5; ++sg)
            #pragma unroll
            for (int p = 0; p < 4; ++p)
                rIdx[sg][p] = arrs[sg][m0 + p * 32 + r8];
    }

    h16x8 av[4], bv[8];

#define LDC3(c)                                                                          \
    {                                                                                    \
        const int seg  = (c) >> 1;                                                       \
        const int half = (c) & 1;                                                        \
        _Pragma("unroll")                                                                \
        for (int p = 0; p < 4; ++p) {                                                    \
            const size_t row = (size_t)rIdx[seg][p];                                     \
            if (seg < 3) {                                                               \
                av[p] = *reinterpret_cast<const h16x8*>(                                 \
                    nodeh + row * D + half * 64 + sub * 8);                              \
            } else if (edgeh) {                                                          \
                av[p] = *reinterpret_cast<const h16x8*>(                                 \
                    edgeh + row * D + half * 64 + sub * 8);                              \
            } else {                                                                     \
                const float4* fp = reinterpret_cast<const float4*>(                      \
                    edge + row * D + half * 64 + sub * 8);                               \
                const float4 u = fp[0], vv = fp[1];                                      \
                h16x8 t;                                                                 \
                t[0] = (h16)u.x;  t[1] = (h16)u.y;  t[2] = (h16)u.z;  t[3] = (h16)u.w;   \
                t[4] = (h16)vv.x; t[5] = (h16)vv.y; t[6] = (h16)vv.z; t[7] = (h16)vv.w;  \
                av[p] = t;                                                               \
            }                                                                            \
        }                                                                                \
        const h16x8* wp = reinterpret_cast<const h16x8*>(W3t) + (c) * 2048 + tid;        \
        _Pragma("unroll")                                                                \
        for (int q = 0; q < 8; ++q) bv[q] = wp[q * 256];                                 \
    }

    LDC3(0);   // prologue prefetch

    #pragma unroll 1
    for (int c = 0; c < 10; ++c) {
        __syncthreads();   // previous chunk's fragment reads complete
        #pragma unroll
        for (int p = 0; p < 4; ++p)
            *reinterpret_cast<h16x8*>(&As[(p * 32 + r8) * LDA + sub * 8]) = av[p];
        h16x8* bd = reinterpret_cast<h16x8*>(&Bs[tid * LDA]);
        #pragma unroll
        for (int q = 0; q < 8; ++q) bd[q] = bv[q];
        __syncthreads();

        if (c < 9) LDC3(c + 1);   // issue next chunk's gathers under MFMA

        #pragma unroll
        for (int kk = 0; kk < 64; kk += 32) {
            h16x8 a0 = *reinterpret_cast<const h16x8*>(&As[(wave*32      + l15) * LDA + kk + quad*8]);
            h16x8 a1 = *reinterpret_cast<const h16x8*>(&As[(wave*32 + 16 + l15) * LDA + kk + quad*8]);
            #pragma unroll
            for (int nt = 0; nt < 16; ++nt) {
                h16x8 b = *reinterpret_cast<const h16x8*>(&Bs[(nt*16 + l15) * LDA + kk + quad*8]);
                acc[0][nt] = __builtin_amdgcn_mfma_f32_16x16x32_f16(a0, b, acc[0][nt], 0, 0, 0);
                acc[1][nt] = __builtin_amdgcn_mfma_f32_16x16x32_f16(a1, b, acc[1][nt], 0, 0, 0);
            }
        }
    }
#undef LDC3

    // ---- epilogue: +b3, LN(256), gate, atomic scatter (R2-proven) ----
    float bias[16], gg[16], bb[16];
    #pragma unroll
    for (int nt = 0; nt < 16; ++nt) {
        const int cc = nt * 16 + l15;
        bias[nt] = b3[cc]; gg[nt] = g3[cc]; bb[nt] = be3[cc];
    }
    #pragma unroll
    for (int mt = 0; mt < 2; ++mt) {
        #pragma unroll
        for (int rg = 0; rg < 4; ++rg) {
            float v[16];
            float s = 0.f, s2 = 0.f;
            #pragma unroll
            for (int nt = 0; nt < 16; ++nt) {
                v[nt] = acc[mt][nt][rg] + bias[nt];
                s += v[nt]; s2 += v[nt] * v[nt];
            }
            #pragma unroll
            for (int m = 1; m < 16; m <<= 1) {   // reduce within the 16-lane quad
                s  += __shfl_xor(s,  m, 64);
                s2 += __shfl_xor(s2, m, 64);
            }
            const float mean = s * (1.f / 256.f);
            const float var  = s2 * (1.f / 256.f) - mean * mean;
            const float inv  = rsqrtf(var + EPS);
            const int rowg   = m0 + wave * 32 + mt * 16 + quad * 4 + rg;
            const size_t e   = (size_t)idx_ji[rowg];
            #pragma unroll
            for (int nt = 0; nt < 8; ++nt) {
                const float f   = (v[nt]     - mean) * inv * gg[nt]     + bb[nt];
                const float co  = (v[nt + 8] - mean) * inv * gg[nt + 8] + bb[nt + 8];
                const float msg = (1.f / (1.f + __expf(-f))) * tanhf(co);
                atomicAdd(&acc3[e * D + nt * 16 + l15], msg);
            }
        }
    }
}

// ---------------------------------------------------------------------------
// c2 (fused with final): (node[i]*node[j]) [E,128] @ W2^T + b2 -> LN(256) ->
// gate -> LN(128) = c2_emb; then read acc3 row, LN(128) = c3_emb; write
// out = tanh(edge + c2_emb + c3_emb) in place over acc3 (= d_out).
// Same coalesced staging restructure as c3.
// ---------------------------------------------------------------------------
__global__ __launch_bounds__(256, 2) void c2_kernel(
    const h16* __restrict__ nodeh,
    const int* __restrict__ ei, const int* __restrict__ ej,
    const h16* __restrict__ W2t, const float* __restrict__ b2,
    const float* __restrict__ g2, const float* __restrict__ be2,
    const float* __restrict__ g22, const float* __restrict__ be22,
    const float* __restrict__ g32, const float* __restrict__ be32,
    const float* __restrict__ edge,
    float* __restrict__ out)
{
    __shared__ h16 As[128 * LDA];
    __shared__ h16 Bs[256 * LDA];

    const int tid  = threadIdx.x;
    const int lane = tid & 63;
    const int wave = tid >> 6;
    const int l15  = lane & 15;
    const int quad = lane >> 4;
    const int m0   = blockIdx.x * 128;

    f32x4 acc[2][16];
    #pragma unroll
    for (int mt = 0; mt < 2; ++mt)
        #pragma unroll
        for (int nt = 0; nt < 16; ++nt)
            acc[mt][nt] = (f32x4){0.f, 0.f, 0.f, 0.f};

    const int r8  = tid >> 3;
    const int sub = tid & 7;

    int rI[4], rJ[4];
    #pragma unroll
    for (int p = 0; p < 4; ++p) {
        rI[p] = ei[m0 + p * 32 + r8];
        rJ[p] = ej[m0 + p * 32 + r8];
    }

    h16x8 av[4], bv[8];

#define LDC2(c)                                                                          \
    {                                                                                    \
        _Pragma("unroll")                                                                \
        for (int p = 0; p < 4; ++p) {                                                    \
            const h16x8 si = *reinterpret_cast<const h16x8*>(                            \
                nodeh + (size_t)rI[p] * D + (c) * 64 + sub * 8);                         \
            const h16x8 sj = *reinterpret_cast<const h16x8*>(                            \
                nodeh + (size_t)rJ[p] * D + (c) * 64 + sub * 8);                         \
            av[p] = si * sj;                                                             \
        }                                                                                \
        const h16x8* wp = reinterpret_cast<const h16x8*>(W2t) + (c) * 2048 + tid;        \
        _Pragma("unroll")                                                                \
        for (int q = 0; q < 8; ++q) bv[q] = wp[q * 256];                                 \
    }

    LDC2(0);

    #pragma unroll 1
    for (int c = 0; c < 2; ++c) {
        __syncthreads();
        #pragma unroll
        for (int p = 0; p < 4; ++p)
            *reinterpret_cast<h16x8*>(&As[(p * 32 + r8) * LDA + sub * 8]) = av[p];
        h16x8* bd = reinterpret_cast<h16x8*>(&Bs[tid * LDA]);
        #pragma unroll
        for (int q = 0; q < 8; ++q) bd[q] = bv[q];
        __syncthreads();

        if (c < 1) LDC2(c + 1);

        #pragma unroll
        for (int kk = 0; kk < 64; kk += 32) {
            h16x8 a0 = *reinterpret_cast<const h16x8*>(&As[(wave*32      + l15) * LDA + kk + quad*8]);
            h16x8 a1 = *reinterpret_cast<const h16x8*>(&As[(wave*32 + 16 + l15) * LDA + kk + quad*8]);
            #pragma unroll
            for (int nt = 0; nt < 16; ++nt) {
                h16x8 b = *reinterpret_cast<const h16x8*>(&Bs[(nt*16 + l15) * LDA + kk + quad*8]);
                acc[0][nt] = __builtin_amdgcn_mfma_f32_16x16x32_f16(a0, b, acc[0][nt], 0, 0, 0);
                acc[1][nt] = __builtin_amdgcn_mfma_f32_16x16x32_f16(a1, b, acc[1][nt], 0, 0, 0);
            }
        }
    }
#undef LDC2

    // ---- epilogue: +b2, LN(256), gate, LN(128), then fused final ----
    float bias[16], gg[16], bb[16];
    #pragma unroll
    for (int nt = 0; nt < 16; ++nt) {
        const int cc = nt * 16 + l15;
        bias[nt] = b2[cc]; gg[nt] = g2[cc]; bb[nt] = be2[cc];
    }
    float g2c[8], b2c[8], g3c[8], b3c[8];
    #pragma unroll
    for (int nt = 0; nt < 8; ++nt) {
        const int cc = nt * 16 + l15;
        g2c[nt] = g22[cc]; b2c[nt] = be22[cc];
        g3c[nt] = g32[cc]; b3c[nt] = be32[cc];
    }
    #pragma unroll
    for (int mt = 0; mt < 2; ++mt) {
        #pragma unroll
        for (int rg = 0; rg < 4; ++rg) {
            float v[16];
            float s = 0.f, s2 = 0.f;
            #pragma unroll
            for (int nt = 0; nt < 16; ++nt) {
                v[nt] = acc[mt][nt][rg] + bias[nt];
                s += v[nt]; s2 += v[nt] * v[nt];
            }
            #pragma unroll
            for (int m = 1; m < 16; m <<= 1) {
                s  += __shfl_xor(s,  m, 64);
                s2 += __shfl_xor(s2, m, 64);
            }
            const float mean = s * (1.f / 256.f);
            const float var  = s2 * (1.f / 256.f) - mean * mean;
            const float inv  = rsqrtf(var + EPS);
            const size_t rowg = (size_t)(m0 + wave * 32 + mt * 16 + quad * 4 + rg);

            // gate -> msg, and read this row's acc3 (c3 accumulator)
            float msg[8], a3[8];
            float t = 0.f, t2 = 0.f, u = 0.f, u2 = 0.f;
            #pragma unroll
            for (int nt = 0; nt < 8; ++nt) {
                const float f  = (v[nt]     - mean) * inv * gg[nt]     + bb[nt];
                const float co = (v[nt + 8] - mean) * inv * gg[nt + 8] + bb[nt + 8];
                const float m_ = (1.f / (1.f + __expf(-f))) * tanhf(co);
                msg[nt] = m_; t += m_; t2 += m_ * m_;
                const float a_ = out[rowg * D + nt * 16 + l15];
                a3[nt] = a_; u += a_; u2 += a_ * a_;
            }
            #pragma unroll
            for (int m = 1; m < 16; m <<= 1) {
                t  += __shfl_xor(t,  m, 64);
                t2 += __shfl_xor(t2, m, 64);
                u  += __shfl_xor(u,  m, 64);
                u2 += __shfl_xor(u2, m, 64);
            }
            const float mean2 = t * (1.f / 128.f);
            const float var2  = t2 * (1.f / 128.f) - mean2 * mean2;
            const float inv2  = rsqrtf(var2 + EPS);
            const float mean3 = u * (1.f / 128.f);
            const float var3  = u2 * (1.f / 128.f) - mean3 * mean3;
            const float inv3  = rsqrtf(var3 + EPS);
            #pragma unroll
            for (int nt = 0; nt < 8; ++nt) {
                const int cc = nt * 16 + l15;
                const float c2v = (msg[nt] - mean2) * inv2 * g2c[nt] + b2c[nt];
                const float c3v = (a3[nt]  - mean3) * inv3 * g3c[nt] + b3c[nt];
                const float ev  = edge[rowg * D + cc];
                out[rowg * D + cc] = tanhf(ev + c2v + c3v);
            }
        }
    }
}

// ---------------------------------------------------------------------------
extern "C" void kernel_launch(void* const* d_in, const int* in_sizes, int n_in,
                              void* d_out, int out_size, void* d_ws, size_t ws_size,
                              hipStream_t stream)
{
    const float* node   = (const float*)d_in[0];
    const float* edge   = (const float*)d_in[1];
    const int*   e_i    = (const int*)d_in[2];
    const int*   e_j    = (const int*)d_in[3];
    const int*   idx_i  = (const int*)d_in[4];
    const int*   idx_j  = (const int*)d_in[5];
    const int*   idx_k  = (const int*)d_in[6];
    const int*   idx_ji = (const int*)d_in[7];
    const int*   idx_kj = (const int*)d_in[8];
    const float* W2     = (const float*)d_in[9];
    const float* b2     = (const float*)d_in[10];
    const float* W3     = (const float*)d_in[11];
    const float* b3     = (const float*)d_in[12];
    const float* g_c2   = (const float*)d_in[13];
    const float* be_c2  = (const float*)d_in[14];
    const float* g_c3   = (const float*)d_in[15];
    const float* be_c3  = (const float*)d_in[16];
    const float* g_c22  = (const float*)d_in[17];
    const float* be_c22 = (const float*)d_in[18];
    const float* g_c32  = (const float*)d_in[19];
    const float* be_c32 = (const float*)d_in[20];

    // ws layout (fp16): W3t [256*640] | W2t [256*128] | nodeh [N*128] |
    //                   edgeh [E*128] (optional)
    h16* W3t   = (h16*)d_ws;
    h16* W2t   = W3t + 256 * K3;
    h16* nodeh = W2t + 256 * D;
    h16* edgeh = nodeh + (size_t)NN * D;
    const size_t need = ((size_t)256 * K3 + 256 * D + (size_t)NN * D
                         + (size_t)EE * D) * sizeof(h16);
    const bool use_edgeh = ws_size >= need;

    float* acc3 = (float*)d_out;   // fp32 scatter accumulator, finalized in place
    float* out  = (float*)d_out;

    hipMemsetAsync(d_out, 0, (size_t)EE * D * sizeof(float), stream);
    cvt_w_t<<<dim3((256 * K3 / 8 + 255) / 256), dim3(256), 0, stream>>>(W3, W3t, K3, 256 * K3 / 8);
    cvt_w_t<<<dim3((256 * D  / 8 + 255) / 256), dim3(256), 0, stream>>>(W2, W2t, D, 256 * D / 8);
    cvt_f32_f16<<<dim3((NN * D   / 8 + 255) / 256), dim3(256), 0, stream>>>(node, nodeh, NN * D / 8);
    if (use_edgeh)
        cvt_f32_f16<<<dim3((EE * D / 8 + 255) / 256), dim3(256), 0, stream>>>(edge, edgeh, EE * D / 8);

    c3_kernel<<<dim3(TT / 128), dim3(256), 0, stream>>>(
        nodeh, edge, use_edgeh ? edgeh : (const h16*)nullptr,
        idx_i, idx_j, idx_k, idx_ji, idx_kj, W3t, b3, g_c3, be_c3, acc3);
    c2_kernel<<<dim3(EE / 128), dim3(256), 0, stream>>>(
        nodeh, e_i, e_j, W2t, b2, g_c2, be_c2, g_c22, be_c22,
        g_c32, be_c32, edge, out);
}

// Round 6
// 614.737 us; speedup vs baseline: 1.3028x; 1.1632x over previous
//
#include <hip/hip_runtime.h>

typedef _Float16 h16;
typedef _Float16 h16x8 __attribute__((ext_vector_type(8)));
typedef float    f32x4 __attribute__((ext_vector_type(4)));

static constexpr int NN  = 32768;
static constexpr int EE  = 262144;
static constexpr int TT  = 262144;
static constexpr int D   = 128;   // DN = DE
static constexpr int K3  = 640;   // 3*DN + 2*DE
static constexpr int LDA = 72;    // padded LDS row stride (64 + 8) in h16
#define EPS 1e-5f

// fast transcendentals: v_exp_f32 + v_rcp_f32 (~1 ulp each; tolerance is 5.9e-3)
__device__ __forceinline__ float fast_rcp(float x) { return __builtin_amdgcn_rcpf(x); }
__device__ __forceinline__ float fast_tanh(float x) {
    const float e = __expf(2.f * x);          // v_exp_f32 (+ mul by log2e)
    return 1.f - 2.f * fast_rcp(e + 1.f);     // large x: e=inf -> 1; x<<0: e=0 -> -1
}
__device__ __forceinline__ float fast_sig(float x) {
    return fast_rcp(1.f + __expf(-x));
}

// ---------------------------------------------------------------------------
// fp32 -> fp16 converter, 8 elems/thread (row-major, layout-preserving)
// ---------------------------------------------------------------------------
__global__ __launch_bounds__(256) void cvt_f32_f16(
    const float* __restrict__ src, h16* __restrict__ dst, int n8)
{
    const int i = blockIdx.x * 256 + threadIdx.x;
    if (i >= n8) return;
    const float4* s = reinterpret_cast<const float4*>(src);
    const float4 a = s[2 * i], b = s[2 * i + 1];
    h16x8 o;
    o[0] = (h16)a.x; o[1] = (h16)a.y; o[2] = (h16)a.z; o[3] = (h16)a.w;
    o[4] = (h16)b.x; o[5] = (h16)b.y; o[6] = (h16)b.z; o[7] = (h16)b.w;
    *reinterpret_cast<h16x8*>(dst + 8 * i) = o;
}

// edge convert + zero acc3 in one pass (replaces the separate 128 MB memset)
__global__ __launch_bounds__(256) void cvt_edge_zero(
    const float* __restrict__ src, h16* __restrict__ dst,
    float* __restrict__ zbuf, int n8)
{
    const int i = blockIdx.x * 256 + threadIdx.x;
    if (i >= n8) return;
    const float4* s = reinterpret_cast<const float4*>(src);
    const float4 a = s[2 * i], b = s[2 * i + 1];
    h16x8 o;
    o[0] = (h16)a.x; o[1] = (h16)a.y; o[2] = (h16)a.z; o[3] = (h16)a.w;
    o[4] = (h16)b.x; o[5] = (h16)b.y; o[6] = (h16)b.z; o[7] = (h16)b.w;
    *reinterpret_cast<h16x8*>(dst + 8 * i) = o;
    const float4 z = {0.f, 0.f, 0.f, 0.f};
    float4* zp = reinterpret_cast<float4*>(zbuf);
    zp[2 * i]     = z;
    zp[2 * i + 1] = z;
}

// ---------------------------------------------------------------------------
// Weight converter with chunk-major re-layout for coalesced staging loads:
// dst[c][q][n][e]  (c = K-chunk of 64, q = 8-col group, n = 0..255, e = 0..7)
// ---------------------------------------------------------------------------
__global__ __launch_bounds__(256) void cvt_w_t(
    const float* __restrict__ src, h16* __restrict__ dst, int K, int n8)
{
    const int t = blockIdx.x * 256 + threadIdx.x;
    if (t >= n8) return;
    const int d   = t * 8;
    const int c   = d >> 14;           // 16384 h16 per chunk
    const int rem = d & 16383;
    const int q   = rem >> 11;         // 2048 h16 per q-group
    const int n   = (rem >> 3) & 255;
    const int k   = c * 64 + q * 8;
    const float4* s = reinterpret_cast<const float4*>(src + (size_t)n * K + k);
    const float4 a = s[0], b = s[1];
    h16x8 o;
    o[0] = (h16)a.x; o[1] = (h16)a.y; o[2] = (h16)a.z; o[3] = (h16)a.w;
    o[4] = (h16)b.x; o[5] = (h16)b.y; o[6] = (h16)b.z; o[7] = (h16)b.w;
    *reinterpret_cast<h16x8*>(dst + d) = o;
}

// ---------------------------------------------------------------------------
// c3: gathered A [T,640](fp16) @ W3^T [640,256](fp16) + b3 -> LN(256) ->
// sigmoid*tanh -> atomicAdd scatter into acc3[E,128] (fp32, = d_out)
// ---------------------------------------------------------------------------
__global__ __launch_bounds__(256, 2) void c3_kernel(
    const h16*  __restrict__ nodeh, const float* __restrict__ edge,
    const h16*  __restrict__ edgeh,
    const int* __restrict__ idx_i, const int* __restrict__ idx_j,
    const int* __restrict__ idx_k, const int* __restrict__ idx_ji,
    const int* __restrict__ idx_kj,
    const h16* __restrict__ W3t, const float* __restrict__ b3,
    const float* __restrict__ g3, const float* __restrict__ be3,
    float* __restrict__ acc3)
{
    __shared__ h16 As[128 * LDA];   // 18 KB
    __shared__ h16 Bs[256 * LDA];   // 36 KB

    const int tid  = threadIdx.x;
    const int lane = tid & 63;
    const int wave = tid >> 6;
    const int l15  = lane & 15;
    const int quad = lane >> 4;
    const int m0   = blockIdx.x * 128;

    f32x4 acc[2][16];
    #pragma unroll
    for (int mt = 0; mt < 2; ++mt)
        #pragma unroll
        for (int nt = 0; nt < 16; ++nt)
            acc[mt][nt] = (f32x4){0.f, 0.f, 0.f, 0.f};

    const int r8  = tid >> 3;   // 0..31: row within the 32-row pass group
    const int sub = tid & 7;    // 16-B segment within the row's 128-B chunk

    int rIdx[5][4];
    {
        const int* arrs[5] = {idx_i, idx_j, idx_k, idx_ji, idx_kj};
        #pragma unroll
        for (int sg = 0; sg < 5; ++sg)
            #pragma unroll
            for (int p = 0; p < 4; ++p)
                rIdx[sg][p] = arrs[sg][m0 + p * 32 + r8];
    }

    h16x8 av[4], bv[8];

#define LDC3(c)                                                                          \
    {                                                                                    \
        const int seg  = (c) >> 1;                                                       \
        const int half = (c) & 1;                                                        \
        _Pragma("unroll")                                                                \
        for (int p = 0; p < 4; ++p) {                                                    \
            const size_t row = (size_t)rIdx[seg][p];                                     \
            if (seg < 3) {                                                               \
                av[p] = *reinterpret_cast<const h16x8*>(                                 \
                    nodeh + row * D + half * 64 + sub * 8);                              \
            } else if (edgeh) {                                                          \
                av[p] = *reinterpret_cast<const h16x8*>(                                 \
                    edgeh + row * D + half * 64 + sub * 8);                              \
            } else {                                                                     \
                const float4* fp = reinterpret_cast<const float4*>(                      \
                    edge + row * D + half * 64 + sub * 8);                               \
                const float4 u = fp[0], vv = fp[1];                                      \
                h16x8 t;                                                                 \
                t[0] = (h16)u.x;  t[1] = (h16)u.y;  t[2] = (h16)u.z;  t[3] = (h16)u.w;   \
                t[4] = (h16)vv.x; t[5] = (h16)vv.y; t[6] = (h16)vv.z; t[7] = (h16)vv.w;  \
                av[p] = t;                                                               \
            }                                                                            \
        }                                                                                \
        const h16x8* wp = reinterpret_cast<const h16x8*>(W3t) + (c) * 2048 + tid;        \
        _Pragma("unroll")                                                                \
        for (int q = 0; q < 8; ++q) bv[q] = wp[q * 256];                                 \
    }

    LDC3(0);   // prologue prefetch

    #pragma unroll 1
    for (int c = 0; c < 10; ++c) {
        __syncthreads();   // previous chunk's fragment reads complete
        #pragma unroll
        for (int p = 0; p < 4; ++p)
            *reinterpret_cast<h16x8*>(&As[(p * 32 + r8) * LDA + sub * 8]) = av[p];
        h16x8* bd = reinterpret_cast<h16x8*>(&Bs[tid * LDA]);
        #pragma unroll
        for (int q = 0; q < 8; ++q) bd[q] = bv[q];
        __syncthreads();

        if (c < 9) LDC3(c + 1);   // issue next chunk's gathers under MFMA

        #pragma unroll
        for (int kk = 0; kk < 64; kk += 32) {
            h16x8 a0 = *reinterpret_cast<const h16x8*>(&As[(wave*32      + l15) * LDA + kk + quad*8]);
            h16x8 a1 = *reinterpret_cast<const h16x8*>(&As[(wave*32 + 16 + l15) * LDA + kk + quad*8]);
            #pragma unroll
            for (int nt = 0; nt < 16; ++nt) {
                h16x8 b = *reinterpret_cast<const h16x8*>(&Bs[(nt*16 + l15) * LDA + kk + quad*8]);
                acc[0][nt] = __builtin_amdgcn_mfma_f32_16x16x32_f16(a0, b, acc[0][nt], 0, 0, 0);
                acc[1][nt] = __builtin_amdgcn_mfma_f32_16x16x32_f16(a1, b, acc[1][nt], 0, 0, 0);
            }
        }
    }
#undef LDC3

    // ---- epilogue: +b3, LN(256), gate, atomic scatter ----
    float bias[16], gg[16], bb[16];
    #pragma unroll
    for (int nt = 0; nt < 16; ++nt) {
        const int cc = nt * 16 + l15;
        bias[nt] = b3[cc]; gg[nt] = g3[cc]; bb[nt] = be3[cc];
    }
    #pragma unroll
    for (int mt = 0; mt < 2; ++mt) {
        #pragma unroll
        for (int rg = 0; rg < 4; ++rg) {
            float v[16];
            float s = 0.f, s2 = 0.f;
            #pragma unroll
            for (int nt = 0; nt < 16; ++nt) {
                v[nt] = acc[mt][nt][rg] + bias[nt];
                s += v[nt]; s2 += v[nt] * v[nt];
            }
            #pragma unroll
            for (int m = 1; m < 16; m <<= 1) {   // reduce within the 16-lane quad
                s  += __shfl_xor(s,  m, 64);
                s2 += __shfl_xor(s2, m, 64);
            }
            const float mean = s * (1.f / 256.f);
            const float var  = s2 * (1.f / 256.f) - mean * mean;
            const float inv  = rsqrtf(var + EPS);
            const int rowg   = m0 + wave * 32 + mt * 16 + quad * 4 + rg;
            const size_t e   = (size_t)idx_ji[rowg];
            #pragma unroll
            for (int nt = 0; nt < 8; ++nt) {
                const float f   = (v[nt]     - mean) * inv * gg[nt]     + bb[nt];
                const float co  = (v[nt + 8] - mean) * inv * gg[nt + 8] + bb[nt + 8];
                const float msg = fast_sig(f) * fast_tanh(co);
                atomicAdd(&acc3[e * D + nt * 16 + l15], msg);
            }
        }
    }
}

// ---------------------------------------------------------------------------
// c2 (fused with final): (node[i]*node[j]) [E,128] @ W2^T + b2 -> LN(256) ->
// gate -> LN(128) = c2_emb; then read acc3 row, LN(128) = c3_emb; write
// out = tanh(edge + c2_emb + c3_emb) in place over acc3 (= d_out).
// ---------------------------------------------------------------------------
__global__ __launch_bounds__(256, 2) void c2_kernel(
    const h16* __restrict__ nodeh,
    const int* __restrict__ ei, const int* __restrict__ ej,
    const h16* __restrict__ W2t, const float* __restrict__ b2,
    const float* __restrict__ g2, const float* __restrict__ be2,
    const float* __restrict__ g22, const float* __restrict__ be22,
    const float* __restrict__ g32, const float* __restrict__ be32,
    const float* __restrict__ edge,
    float* __restrict__ out)
{
    __shared__ h16 As[128 * LDA];
    __shared__ h16 Bs[256 * LDA];

    const int tid  = threadIdx.x;
    const int lane = tid & 63;
    const int wave = tid >> 6;
    const int l15  = lane & 15;
    const int quad = lane >> 4;
    const int m0   = blockIdx.x * 128;

    f32x4 acc[2][16];
    #pragma unroll
    for (int mt = 0; mt < 2; ++mt)
        #pragma unroll
        for (int nt = 0; nt < 16; ++nt)
            acc[mt][nt] = (f32x4){0.f, 0.f, 0.f, 0.f};

    const int r8  = tid >> 3;
    const int sub = tid & 7;

    int rI[4], rJ[4];
    #pragma unroll
    for (int p = 0; p < 4; ++p) {
        rI[p] = ei[m0 + p * 32 + r8];
        rJ[p] = ej[m0 + p * 32 + r8];
    }

    h16x8 av[4], bv[8];

#define LDC2(c)                                                                          \
    {                                                                                    \
        _Pragma("unroll")                                                                \
        for (int p = 0; p < 4; ++p) {                                                    \
            const h16x8 si = *reinterpret_cast<const h16x8*>(                            \
                nodeh + (size_t)rI[p] * D + (c) * 64 + sub * 8);                         \
            const h16x8 sj = *reinterpret_cast<const h16x8*>(                            \
                nodeh + (size_t)rJ[p] * D + (c) * 64 + sub * 8);                         \
            av[p] = si * sj;                                                             \
        }                                                                                \
        const h16x8* wp = reinterpret_cast<const h16x8*>(W2t) + (c) * 2048 + tid;        \
        _Pragma("unroll")                                                                \
        for (int q = 0; q < 8; ++q) bv[q] = wp[q * 256];                                 \
    }

    LDC2(0);

    #pragma unroll 1
    for (int c = 0; c < 2; ++c) {
        __syncthreads();
        #pragma unroll
        for (int p = 0; p < 4; ++p)
            *reinterpret_cast<h16x8*>(&As[(p * 32 + r8) * LDA + sub * 8]) = av[p];
        h16x8* bd = reinterpret_cast<h16x8*>(&Bs[tid * LDA]);
        #pragma unroll
        for (int q = 0; q < 8; ++q) bd[q] = bv[q];
        __syncthreads();

        if (c < 1) LDC2(c + 1);

        #pragma unroll
        for (int kk = 0; kk < 64; kk += 32) {
            h16x8 a0 = *reinterpret_cast<const h16x8*>(&As[(wave*32      + l15) * LDA + kk + quad*8]);
            h16x8 a1 = *reinterpret_cast<const h16x8*>(&As[(wave*32 + 16 + l15) * LDA + kk + quad*8]);
            #pragma unroll
            for (int nt = 0; nt < 16; ++nt) {
                h16x8 b = *reinterpret_cast<const h16x8*>(&Bs[(nt*16 + l15) * LDA + kk + quad*8]);
                acc[0][nt] = __builtin_amdgcn_mfma_f32_16x16x32_f16(a0, b, acc[0][nt], 0, 0, 0);
                acc[1][nt] = __builtin_amdgcn_mfma_f32_16x16x32_f16(a1, b, acc[1][nt], 0, 0, 0);
            }
        }
    }
#undef LDC2

    // ---- epilogue: +b2, LN(256), gate, LN(128), then fused final ----
    float bias[16], gg[16], bb[16];
    #pragma unroll
    for (int nt = 0; nt < 16; ++nt) {
        const int cc = nt * 16 + l15;
        bias[nt] = b2[cc]; gg[nt] = g2[cc]; bb[nt] = be2[cc];
    }
    float g2c[8], b2c[8], g3c[8], b3c[8];
    #pragma unroll
    for (int nt = 0; nt < 8; ++nt) {
        const int cc = nt * 16 + l15;
        g2c[nt] = g22[cc]; b2c[nt] = be22[cc];
        g3c[nt] = g32[cc]; b3c[nt] = be32[cc];
    }
    #pragma unroll
    for (int mt = 0; mt < 2; ++mt) {
        #pragma unroll
        for (int rg = 0; rg < 4; ++rg) {
            float v[16];
            float s = 0.f, s2 = 0.f;
            #pragma unroll
            for (int nt = 0; nt < 16; ++nt) {
                v[nt] = acc[mt][nt][rg] + bias[nt];
                s += v[nt]; s2 += v[nt] * v[nt];
            }
            #pragma unroll
            for (int m = 1; m < 16; m <<= 1) {
                s  += __shfl_xor(s,  m, 64);
                s2 += __shfl_xor(s2, m, 64);
            }
            const float mean = s * (1.f / 256.f);
            const float var  = s2 * (1.f / 256.f) - mean * mean;
            const float inv  = rsqrtf(var + EPS);
            const size_t rowg = (size_t)(m0 + wave * 32 + mt * 16 + quad * 4 + rg);

            // gate -> msg, and read this row's acc3 (c3 accumulator)
            float msg[8], a3[8];
            float t = 0.f, t2 = 0.f, u = 0.f, u2 = 0.f;
            #pragma unroll
            for (int nt = 0; nt < 8; ++nt) {
                const float f  = (v[nt]     - mean) * inv * gg[nt]     + bb[nt];
                const float co = (v[nt + 8] - mean) * inv * gg[nt + 8] + bb[nt + 8];
                const float m_ = fast_sig(f) * fast_tanh(co);
                msg[nt] = m_; t += m_; t2 += m_ * m_;
                const float a_ = out[rowg * D + nt * 16 + l15];
                a3[nt] = a_; u += a_; u2 += a_ * a_;
            }
            #pragma unroll
            for (int m = 1; m < 16; m <<= 1) {
                t  += __shfl_xor(t,  m, 64);
                t2 += __shfl_xor(t2, m, 64);
                u  += __shfl_xor(u,  m, 64);
                u2 += __shfl_xor(u2, m, 64);
            }
            const float mean2 = t * (1.f / 128.f);
            const float var2  = t2 * (1.f / 128.f) - mean2 * mean2;
            const float inv2  = rsqrtf(var2 + EPS);
            const float mean3 = u * (1.f / 128.f);
            const float var3  = u2 * (1.f / 128.f) - mean3 * mean3;
            const float inv3  = rsqrtf(var3 + EPS);
            #pragma unroll
            for (int nt = 0; nt < 8; ++nt) {
                const int cc = nt * 16 + l15;
                const float c2v = (msg[nt] - mean2) * inv2 * g2c[nt] + b2c[nt];
                const float c3v = (a3[nt]  - mean3) * inv3 * g3c[nt] + b3c[nt];
                const float ev  = edge[rowg * D + cc];
                out[rowg * D + cc] = fast_tanh(ev + c2v + c3v);
            }
        }
    }
}

// ---------------------------------------------------------------------------
extern "C" void kernel_launch(void* const* d_in, const int* in_sizes, int n_in,
                              void* d_out, int out_size, void* d_ws, size_t ws_size,
                              hipStream_t stream)
{
    const float* node   = (const float*)d_in[0];
    const float* edge   = (const float*)d_in[1];
    const int*   e_i    = (const int*)d_in[2];
    const int*   e_j    = (const int*)d_in[3];
    const int*   idx_i  = (const int*)d_in[4];
    const int*   idx_j  = (const int*)d_in[5];
    const int*   idx_k  = (const int*)d_in[6];
    const int*   idx_ji = (const int*)d_in[7];
    const int*   idx_kj = (const int*)d_in[8];
    const float* W2     = (const float*)d_in[9];
    const float* b2     = (const float*)d_in[10];
    const float* W3     = (const float*)d_in[11];
    const float* b3     = (const float*)d_in[12];
    const float* g_c2   = (const float*)d_in[13];
    const float* be_c2  = (const float*)d_in[14];
    const float* g_c3   = (const float*)d_in[15];
    const float* be_c3  = (const float*)d_in[16];
    const float* g_c22  = (const float*)d_in[17];
    const float* be_c22 = (const float*)d_in[18];
    const float* g_c32  = (const float*)d_in[19];
    const float* be_c32 = (const float*)d_in[20];

    // ws layout (fp16): W3t [256*640] | W2t [256*128] | nodeh [N*128] |
    //                   edgeh [E*128] (optional)
    h16* W3t   = (h16*)d_ws;
    h16* W2t   = W3t + 256 * K3;
    h16* nodeh = W2t + 256 * D;
    h16* edgeh = nodeh + (size_t)NN * D;
    const size_t need = ((size_t)256 * K3 + 256 * D + (size_t)NN * D
                         + (size_t)EE * D) * sizeof(h16);
    const bool use_edgeh = ws_size >= need;

    float* acc3 = (float*)d_out;   // fp32 scatter accumulator, finalized in place
    float* out  = (float*)d_out;

    cvt_w_t<<<dim3((256 * K3 / 8 + 255) / 256), dim3(256), 0, stream>>>(W3, W3t, K3, 256 * K3 / 8);
    cvt_w_t<<<dim3((256 * D  / 8 + 255) / 256), dim3(256), 0, stream>>>(W2, W2t, D, 256 * D / 8);
    cvt_f32_f16<<<dim3((NN * D   / 8 + 255) / 256), dim3(256), 0, stream>>>(node, nodeh, NN * D / 8);
    if (use_edgeh) {
        // converts edge to fp16 AND zeroes acc3 (one pass, no separate memset)
        cvt_edge_zero<<<dim3((EE * D / 8 + 255) / 256), dim3(256), 0, stream>>>(
            edge, edgeh, acc3, EE * D / 8);
    } else {
        hipMemsetAsync(d_out, 0, (size_t)EE * D * sizeof(float), stream);
    }

    c3_kernel<<<dim3(TT / 128), dim3(256), 0, stream>>>(
        nodeh, edge, use_edgeh ? edgeh : (const h16*)nullptr,
        idx_i, idx_j, idx_k, idx_ji, idx_kj, W3t, b3, g_c3, be_c3, acc3);
    c2_kernel<<<dim3(EE / 128), dim3(256), 0, stream>>>(
        nodeh, e_i, e_j, W2t, b2, g_c2, be_c2, g_c22, be_c22,
        g_c32, be_c32, edge, out);
}

// Round 7
// 603.401 us; speedup vs baseline: 1.3273x; 1.0188x over previous
//
#include <hip/hip_runtime.h>

typedef _Float16 h16;
typedef _Float16 h16x8 __attribute__((ext_vector_type(8)));
typedef float    f32x4 __attribute__((ext_vector_type(4)));

static constexpr int NN  = 32768;
static constexpr int EE  = 262144;
static constexpr int TT  = 262144;
static constexpr int D   = 128;   // DN = DE
static constexpr int K3  = 640;   // 3*DN + 2*DE
#define EPS 1e-5f

// fast transcendentals: v_exp_f32 + v_rcp_f32 (verified R6, absmax unchanged)
__device__ __forceinline__ float fast_rcp(float x) { return __builtin_amdgcn_rcpf(x); }
__device__ __forceinline__ float fast_tanh(float x) {
    const float e = __expf(2.f * x);
    return 1.f - 2.f * fast_rcp(e + 1.f);
}
__device__ __forceinline__ float fast_sig(float x) {
    return fast_rcp(1.f + __expf(-x));
}

// ---------------------------------------------------------------------------
// fp32 -> fp16 converter, 8 elems/thread (row-major, layout-preserving)
// ---------------------------------------------------------------------------
__global__ __launch_bounds__(256) void cvt_f32_f16(
    const float* __restrict__ src, h16* __restrict__ dst, int n8)
{
    const int i = blockIdx.x * 256 + threadIdx.x;
    if (i >= n8) return;
    const float4* s = reinterpret_cast<const float4*>(src);
    const float4 a = s[2 * i], b = s[2 * i + 1];
    h16x8 o;
    o[0] = (h16)a.x; o[1] = (h16)a.y; o[2] = (h16)a.z; o[3] = (h16)a.w;
    o[4] = (h16)b.x; o[5] = (h16)b.y; o[6] = (h16)b.z; o[7] = (h16)b.w;
    *reinterpret_cast<h16x8*>(dst + 8 * i) = o;
}

// edge convert + zero acc3 in one pass
__global__ __launch_bounds__(256) void cvt_edge_zero(
    const float* __restrict__ src, h16* __restrict__ dst,
    float* __restrict__ zbuf, int n8)
{
    const int i = blockIdx.x * 256 + threadIdx.x;
    if (i >= n8) return;
    const float4* s = reinterpret_cast<const float4*>(src);
    const float4 a = s[2 * i], b = s[2 * i + 1];
    h16x8 o;
    o[0] = (h16)a.x; o[1] = (h16)a.y; o[2] = (h16)a.z; o[3] = (h16)a.w;
    o[4] = (h16)b.x; o[5] = (h16)b.y; o[6] = (h16)b.z; o[7] = (h16)b.w;
    *reinterpret_cast<h16x8*>(dst + 8 * i) = o;
    const float4 z = {0.f, 0.f, 0.f, 0.f};
    float4* zp = reinterpret_cast<float4*>(zbuf);
    zp[2 * i]     = z;
    zp[2 * i + 1] = z;
}

// ---------------------------------------------------------------------------
// Weight converter -> MFMA-fragment-order layout:
// dst[c][slot][8] where slot = (nt*2+kki)*64 + quad*16 + l15 holds
// W[nt*16+l15][c*64 + kki*32 + quad*8 + e].  In-kernel, both the global
// load (bv[q] = wp[q*256+tid]) and the LDS write/read become lane-contiguous
// 1024-B accesses: perfectly coalesced and bank-conflict-free.
// ---------------------------------------------------------------------------
__global__ __launch_bounds__(256) void cvt_w_fo(
    const float* __restrict__ src, h16* __restrict__ dst, int K, int n8)
{
    const int t = blockIdx.x * 256 + threadIdx.x;
    if (t >= n8) return;
    const int d    = t * 8;
    const int c    = d >> 14;          // chunk of 16384 h16 (256x64)
    const int s    = (d >> 3) & 2047;  // slot within chunk
    const int tile = s >> 6;           // nt*2 + kki
    const int ln   = s & 63;
    const int quad = ln >> 4, l15 = ln & 15;
    const int n    = (tile >> 1) * 16 + l15;
    const int k    = c * 64 + (tile & 1) * 32 + quad * 8;
    const float4* sp = reinterpret_cast<const float4*>(src + (size_t)n * K + k);
    const float4 a = sp[0], b = sp[1];
    h16x8 o;
    o[0] = (h16)a.x; o[1] = (h16)a.y; o[2] = (h16)a.z; o[3] = (h16)a.w;
    o[4] = (h16)b.x; o[5] = (h16)b.y; o[6] = (h16)b.z; o[7] = (h16)b.w;
    *reinterpret_cast<h16x8*>(dst + d) = o;
}

// ---------------------------------------------------------------------------
// c3: gathered A [T,640](fp16) @ W3^T [640,256](fp16) + b3 -> LN(256) ->
// sigmoid*tanh -> atomicAdd scatter into acc3[E,128] (fp32, = d_out)
// A-fragments gathered DIRECTLY from global (no LDS transpose needed:
// lane (l15,quad) loads 16 B of row wave*32+l15 -> 16 rows x 64 B lines).
// B staged through 32 KB fragment-order LDS -> 4-5 blocks/CU.
// ---------------------------------------------------------------------------
__global__ __launch_bounds__(256, 2) void c3_kernel(
    const h16*  __restrict__ nodeh, const float* __restrict__ edge,
    const h16*  __restrict__ edgeh,
    const int* __restrict__ idx_i, const int* __restrict__ idx_j,
    const int* __restrict__ idx_k, const int* __restrict__ idx_ji,
    const int* __restrict__ idx_kj,
    const h16* __restrict__ W3t, const float* __restrict__ b3,
    const float* __restrict__ g3, const float* __restrict__ be3,
    float* __restrict__ acc3)
{
    __shared__ h16 Bs[256 * 64];   // 32 KB, fragment-order
    h16x8* Bsv = reinterpret_cast<h16x8*>(Bs);

    const int tid  = threadIdx.x;
    const int lane = tid & 63;
    const int wave = tid >> 6;
    const int l15  = lane & 15;
    const int quad = lane >> 4;
    const int m0   = blockIdx.x * 128;

    f32x4 acc[2][16];
    #pragma unroll
    for (int mt = 0; mt < 2; ++mt)
        #pragma unroll
        for (int nt = 0; nt < 16; ++nt)
            acc[mt][nt] = (f32x4){0.f, 0.f, 0.f, 0.f};

    // per-thread A rows: this lane's two MFMA rows for each index array
    const int row0 = m0 + wave * 32 + l15;
    const int rI0  = idx_i [row0],      rI1  = idx_i [row0 + 16];
    const int rJ0  = idx_j [row0],      rJ1  = idx_j [row0 + 16];
    const int rK0  = idx_k [row0],      rK1  = idx_k [row0 + 16];
    const int rJI0 = idx_ji[row0],      rJI1 = idx_ji[row0 + 16];
    const int rKJ0 = idx_kj[row0],      rKJ1 = idx_kj[row0 + 16];

    h16x8 cur[4], nxt[4], bv[8];

#define LDA3(c, dstv)                                                                    \
    {                                                                                    \
        const int seg  = (c) >> 1;                                                       \
        const int half = (c) & 1;                                                        \
        const size_t R0 = (size_t)((seg == 0) ? rI0 : (seg == 1) ? rJ0                   \
                         : (seg == 2) ? rK0 : (seg == 3) ? rJI0 : rKJ0);                 \
        const size_t R1 = (size_t)((seg == 0) ? rI1 : (seg == 1) ? rJ1                   \
                         : (seg == 2) ? rK1 : (seg == 3) ? rJI1 : rKJ1);                 \
        if (seg < 3) {                                                                   \
            _Pragma("unroll")                                                            \
            for (int kki = 0; kki < 2; ++kki) {                                          \
                dstv[kki]     = *reinterpret_cast<const h16x8*>(                         \
                    nodeh + R0 * D + half * 64 + kki * 32 + quad * 8);                   \
                dstv[2 + kki] = *reinterpret_cast<const h16x8*>(                         \
                    nodeh + R1 * D + half * 64 + kki * 32 + quad * 8);                   \
            }                                                                            \
        } else if (edgeh) {                                                              \
            _Pragma("unroll")                                                            \
            for (int kki = 0; kki < 2; ++kki) {                                          \
                dstv[kki]     = *reinterpret_cast<const h16x8*>(                         \
                    edgeh + R0 * D + half * 64 + kki * 32 + quad * 8);                   \
                dstv[2 + kki] = *reinterpret_cast<const h16x8*>(                         \
                    edgeh + R1 * D + half * 64 + kki * 32 + quad * 8);                   \
            }                                                                            \
        } else {                                                                         \
            _Pragma("unroll")                                                            \
            for (int kki = 0; kki < 2; ++kki) {                                          \
                _Pragma("unroll")                                                        \
                for (int m2 = 0; m2 < 2; ++m2) {                                         \
                    const size_t RR = m2 ? R1 : R0;                                      \
                    const float4* fp = reinterpret_cast<const float4*>(                  \
                        edge + RR * D + half * 64 + kki * 32 + quad * 8);                \
                    const float4 u = fp[0], vv = fp[1];                                  \
                    h16x8 t;                                                             \
                    t[0] = (h16)u.x;  t[1] = (h16)u.y;  t[2] = (h16)u.z;  t[3] = (h16)u.w;\
                    t[4] = (h16)vv.x; t[5] = (h16)vv.y; t[6] = (h16)vv.z; t[7] = (h16)vv.w;\
                    dstv[2 * m2 + kki] = t;                                              \
                }                                                                        \
            }                                                                            \
        }                                                                                \
    }

#define LDB3(c)                                                                          \
    {                                                                                    \
        const h16x8* wp = reinterpret_cast<const h16x8*>(W3t) + (size_t)(c) * 2048 + tid;\
        _Pragma("unroll")                                                                \
        for (int q = 0; q < 8; ++q) bv[q] = wp[q * 256];                                 \
    }

    LDA3(0, cur);
    LDB3(0);

    #pragma unroll 1
    for (int c = 0; c < 10; ++c) {
        __syncthreads();   // all waves done reading Bs of chunk c-1
        #pragma unroll
        for (int q = 0; q < 8; ++q) Bsv[q * 256 + tid] = bv[q];
        __syncthreads();

        if (c < 9) { LDB3(c + 1); LDA3(c + 1, nxt); }

        #pragma unroll
        for (int kki = 0; kki < 2; ++kki) {
            const h16x8 a0 = cur[kki];
            const h16x8 a1 = cur[2 + kki];
            #pragma unroll
            for (int nt = 0; nt < 16; ++nt) {
                const h16x8 b = Bsv[(nt * 2 + kki) * 64 + lane];
                acc[0][nt] = __builtin_amdgcn_mfma_f32_16x16x32_f16(a0, b, acc[0][nt], 0, 0, 0);
                acc[1][nt] = __builtin_amdgcn_mfma_f32_16x16x32_f16(a1, b, acc[1][nt], 0, 0, 0);
            }
        }
        if (c < 9) {
            #pragma unroll
            for (int q = 0; q < 4; ++q) cur[q] = nxt[q];
        }
    }
#undef LDA3
#undef LDB3

    // ---- epilogue: +b3, LN(256), gate, atomic scatter ----
    float bias[16], gg[16], bb[16];
    #pragma unroll
    for (int nt = 0; nt < 16; ++nt) {
        const int cc = nt * 16 + l15;
        bias[nt] = b3[cc]; gg[nt] = g3[cc]; bb[nt] = be3[cc];
    }
    #pragma unroll
    for (int mt = 0; mt < 2; ++mt) {
        #pragma unroll
        for (int rg = 0; rg < 4; ++rg) {
            float v[16];
            float s = 0.f, s2 = 0.f;
            #pragma unroll
            for (int nt = 0; nt < 16; ++nt) {
                v[nt] = acc[mt][nt][rg] + bias[nt];
                s += v[nt]; s2 += v[nt] * v[nt];
            }
            #pragma unroll
            for (int m = 1; m < 16; m <<= 1) {
                s  += __shfl_xor(s,  m, 64);
                s2 += __shfl_xor(s2, m, 64);
            }
            const float mean = s * (1.f / 256.f);
            const float var  = s2 * (1.f / 256.f) - mean * mean;
            const float inv  = rsqrtf(var + EPS);
            const int rowg   = m0 + wave * 32 + mt * 16 + quad * 4 + rg;
            const size_t e   = (size_t)idx_ji[rowg];
            #pragma unroll
            for (int nt = 0; nt < 8; ++nt) {
                const float f   = (v[nt]     - mean) * inv * gg[nt]     + bb[nt];
                const float co  = (v[nt + 8] - mean) * inv * gg[nt + 8] + bb[nt + 8];
                const float msg = fast_sig(f) * fast_tanh(co);
                atomicAdd(&acc3[e * D + nt * 16 + l15], msg);
            }
        }
    }
}

// ---------------------------------------------------------------------------
// c2 (fused with final): (node[i]*node[j]) [E,128] @ W2^T + b2 -> LN(256) ->
// gate -> LN(128) = c2_emb; read acc3 row, LN(128) = c3_emb; write
// out = tanh(edge + c2_emb + c3_emb) in place over acc3 (= d_out).
// Same direct-A-gather + fragment-order-B structure as c3.
// ---------------------------------------------------------------------------
__global__ __launch_bounds__(256, 2) void c2_kernel(
    const h16* __restrict__ nodeh,
    const int* __restrict__ ei, const int* __restrict__ ej,
    const h16* __restrict__ W2t, const float* __restrict__ b2,
    const float* __restrict__ g2, const float* __restrict__ be2,
    const float* __restrict__ g22, const float* __restrict__ be22,
    const float* __restrict__ g32, const float* __restrict__ be32,
    const float* __restrict__ edge,
    float* __restrict__ out)
{
    __shared__ h16 Bs[256 * 64];
    h16x8* Bsv = reinterpret_cast<h16x8*>(Bs);

    const int tid  = threadIdx.x;
    const int lane = tid & 63;
    const int wave = tid >> 6;
    const int l15  = lane & 15;
    const int quad = lane >> 4;
    const int m0   = blockIdx.x * 128;

    f32x4 acc[2][16];
    #pragma unroll
    for (int mt = 0; mt < 2; ++mt)
        #pragma unroll
        for (int nt = 0; nt < 16; ++nt)
            acc[mt][nt] = (f32x4){0.f, 0.f, 0.f, 0.f};

    const int row0 = m0 + wave * 32 + l15;
    const size_t rI0 = (size_t)ei[row0], rI1 = (size_t)ei[row0 + 16];
    const size_t rJ0 = (size_t)ej[row0], rJ1 = (size_t)ej[row0 + 16];

    h16x8 cur[4], nxt[4], bv[8];

#define LDA2(c, dstv)                                                                    \
    {                                                                                    \
        _Pragma("unroll")                                                                \
        for (int kki = 0; kki < 2; ++kki) {                                              \
            const int off = (c) * 64 + kki * 32 + quad * 8;                              \
            const h16x8 si0 = *reinterpret_cast<const h16x8*>(nodeh + rI0 * D + off);    \
            const h16x8 sj0 = *reinterpret_cast<const h16x8*>(nodeh + rJ0 * D + off);    \
            const h16x8 si1 = *reinterpret_cast<const h16x8*>(nodeh + rI1 * D + off);    \
            const h16x8 sj1 = *reinterpret_cast<const h16x8*>(nodeh + rJ1 * D + off);    \
            dstv[kki]     = si0 * sj0;                                                   \
            dstv[2 + kki] = si1 * sj1;                                                   \
        }                                                                                \
    }

#define LDB2(c)                                                                          \
    {                                                                                    \
        const h16x8* wp = reinterpret_cast<const h16x8*>(W2t) + (size_t)(c) * 2048 + tid;\
        _Pragma("unroll")                                                                \
        for (int q = 0; q < 8; ++q) bv[q] = wp[q * 256];                                 \
    }

    LDA2(0, cur);
    LDB2(0);

    #pragma unroll 1
    for (int c = 0; c < 2; ++c) {
        __syncthreads();
        #pragma unroll
        for (int q = 0; q < 8; ++q) Bsv[q * 256 + tid] = bv[q];
        __syncthreads();

        if (c < 1) { LDB2(c + 1); LDA2(c + 1, nxt); }

        #pragma unroll
        for (int kki = 0; kki < 2; ++kki) {
            const h16x8 a0 = cur[kki];
            const h16x8 a1 = cur[2 + kki];
            #pragma unroll
            for (int nt = 0; nt < 16; ++nt) {
                const h16x8 b = Bsv[(nt * 2 + kki) * 64 + lane];
                acc[0][nt] = __builtin_amdgcn_mfma_f32_16x16x32_f16(a0, b, acc[0][nt], 0, 0, 0);
                acc[1][nt] = __builtin_amdgcn_mfma_f32_16x16x32_f16(a1, b, acc[1][nt], 0, 0, 0);
            }
        }
        if (c < 1) {
            #pragma unroll
            for (int q = 0; q < 4; ++q) cur[q] = nxt[q];
        }
    }
#undef LDA2
#undef LDB2

    // ---- epilogue: +b2, LN(256), gate, LN(128), then fused final ----
    float bias[16], gg[16], bb[16];
    #pragma unroll
    for (int nt = 0; nt < 16; ++nt) {
        const int cc = nt * 16 + l15;
        bias[nt] = b2[cc]; gg[nt] = g2[cc]; bb[nt] = be2[cc];
    }
    float g2c[8], b2c[8], g3c[8], b3c[8];
    #pragma unroll
    for (int nt = 0; nt < 8; ++nt) {
        const int cc = nt * 16 + l15;
        g2c[nt] = g22[cc]; b2c[nt] = be22[cc];
        g3c[nt] = g32[cc]; b3c[nt] = be32[cc];
    }
    #pragma unroll
    for (int mt = 0; mt < 2; ++mt) {
        #pragma unroll
        for (int rg = 0; rg < 4; ++rg) {
            float v[16];
            float s = 0.f, s2 = 0.f;
            #pragma unroll
            for (int nt = 0; nt < 16; ++nt) {
                v[nt] = acc[mt][nt][rg] + bias[nt];
                s += v[nt]; s2 += v[nt] * v[nt];
            }
            #pragma unroll
            for (int m = 1; m < 16; m <<= 1) {
                s  += __shfl_xor(s,  m, 64);
                s2 += __shfl_xor(s2, m, 64);
            }
            const float mean = s * (1.f / 256.f);
            const float var  = s2 * (1.f / 256.f) - mean * mean;
            const float inv  = rsqrtf(var + EPS);
            const size_t rowg = (size_t)(m0 + wave * 32 + mt * 16 + quad * 4 + rg);

            float msg[8], a3[8];
            float t = 0.f, t2 = 0.f, u = 0.f, u2 = 0.f;
            #pragma unroll
            for (int nt = 0; nt < 8; ++nt) {
                const float f  = (v[nt]     - mean) * inv * gg[nt]     + bb[nt];
                const float co = (v[nt + 8] - mean) * inv * gg[nt + 8] + bb[nt + 8];
                const float m_ = fast_sig(f) * fast_tanh(co);
                msg[nt] = m_; t += m_; t2 += m_ * m_;
                const float a_ = out[rowg * D + nt * 16 + l15];
                a3[nt] = a_; u += a_; u2 += a_ * a_;
            }
            #pragma unroll
            for (int m = 1; m < 16; m <<= 1) {
                t  += __shfl_xor(t,  m, 64);
                t2 += __shfl_xor(t2, m, 64);
                u  += __shfl_xor(u,  m, 64);
                u2 += __shfl_xor(u2, m, 64);
            }
            const float mean2 = t * (1.f / 128.f);
            const float var2  = t2 * (1.f / 128.f) - mean2 * mean2;
            const float inv2  = rsqrtf(var2 + EPS);
            const float mean3 = u * (1.f / 128.f);
            const float var3  = u2 * (1.f / 128.f) - mean3 * mean3;
            const float inv3  = rsqrtf(var3 + EPS);
            #pragma unroll
            for (int nt = 0; nt < 8; ++nt) {
                const int cc = nt * 16 + l15;
                const float c2v = (msg[nt] - mean2) * inv2 * g2c[nt] + b2c[nt];
                const float c3v = (a3[nt]  - mean3) * inv3 * g3c[nt] + b3c[nt];
                const float ev  = edge[rowg * D + cc];
                out[rowg * D + cc] = fast_tanh(ev + c2v + c3v);
            }
        }
    }
}

// ---------------------------------------------------------------------------
extern "C" void kernel_launch(void* const* d_in, const int* in_sizes, int n_in,
                              void* d_out, int out_size, void* d_ws, size_t ws_size,
                              hipStream_t stream)
{
    const float* node   = (const float*)d_in[0];
    const float* edge   = (const float*)d_in[1];
    const int*   e_i    = (const int*)d_in[2];
    const int*   e_j    = (const int*)d_in[3];
    const int*   idx_i  = (const int*)d_in[4];
    const int*   idx_j  = (const int*)d_in[5];
    const int*   idx_k  = (const int*)d_in[6];
    const int*   idx_ji = (const int*)d_in[7];
    const int*   idx_kj = (const int*)d_in[8];
    const float* W2     = (const float*)d_in[9];
    const float* b2     = (const float*)d_in[10];
    const float* W3     = (const float*)d_in[11];
    const float* b3     = (const float*)d_in[12];
    const float* g_c2   = (const float*)d_in[13];
    const float* be_c2  = (const float*)d_in[14];
    const float* g_c3   = (const float*)d_in[15];
    const float* be_c3  = (const float*)d_in[16];
    const float* g_c22  = (const float*)d_in[17];
    const float* be_c22 = (const float*)d_in[18];
    const float* g_c32  = (const float*)d_in[19];
    const float* be_c32 = (const float*)d_in[20];

    // ws layout (fp16): W3t [256*640] | W2t [256*128] | nodeh [N*128] |
    //                   edgeh [E*128] (optional)
    h16* W3t   = (h16*)d_ws;
    h16* W2t   = W3t + 256 * K3;
    h16* nodeh = W2t + 256 * D;
    h16* edgeh = nodeh + (size_t)NN * D;
    const size_t need = ((size_t)256 * K3 + 256 * D + (size_t)NN * D
                         + (size_t)EE * D) * sizeof(h16);
    const bool use_edgeh = ws_size >= need;

    float* acc3 = (float*)d_out;   // fp32 scatter accumulator, finalized in place
    float* out  = (float*)d_out;

    cvt_w_fo<<<dim3((256 * K3 / 8 + 255) / 256), dim3(256), 0, stream>>>(W3, W3t, K3, 256 * K3 / 8);
    cvt_w_fo<<<dim3((256 * D  / 8 + 255) / 256), dim3(256), 0, stream>>>(W2, W2t, D, 256 * D / 8);
    cvt_f32_f16<<<dim3((NN * D   / 8 + 255) / 256), dim3(256), 0, stream>>>(node, nodeh, NN * D / 8);
    if (use_edgeh) {
        cvt_edge_zero<<<dim3((EE * D / 8 + 255) / 256), dim3(256), 0, stream>>>(
            edge, edgeh, acc3, EE * D / 8);
    } else {
        hipMemsetAsync(d_out, 0, (size_t)EE * D * sizeof(float), stream);
    }

    c3_kernel<<<dim3(TT / 128), dim3(256), 0, stream>>>(
        nodeh, edge, use_edgeh ? edgeh : (const h16*)nullptr,
        idx_i, idx_j, idx_k, idx_ji, idx_kj, W3t, b3, g_c3, be_c3, acc3);
    c2_kernel<<<dim3(EE / 128), dim3(256), 0, stream>>>(
        nodeh, e_i, e_j, W2t, b2, g_c2, be_c2, g_c22, be_c22,
        g_c32, be_c32, edge, out);
}